// Round 1
// baseline (231.682 us; speedup 1.0000x reference)
//
#include <hip/hip_runtime.h>

// Problem constants (from reference setup_inputs)
#define N_TOK 65536
#define KNB 32
#define DIM 128
#define RHO 1.0f
#define BETA 0.5f

// One wave (64 lanes) per row; lane owns dims (2*lane, 2*lane+1).
// Block = 256 threads = 4 rows.
__global__ __launch_bounds__(256) void mirror_main(
    const float* __restrict__ M,
    const float* __restrict__ P,
    const float* __restrict__ Y,
    const float* __restrict__ Lam,
    const int*   __restrict__ Kset,
    float* __restrict__ Pnew,
    float* __restrict__ LamNew,
    float* __restrict__ blockPartials)
{
    const int wid  = threadIdx.x >> 6;     // wave id in block (0..3)
    const int lane = threadIdx.x & 63;
    const int n    = blockIdx.x * 4 + wid; // row index
    const int d0   = lane * 2;

    const float2 y   = *(const float2*)&Y[n * DIM + d0];
    const float2 lam = *(const float2*)&Lam[n * DIM + d0];

    const int*   ks   = &Kset[n * KNB];
    const float* prow = &P[n * KNB];

    // ---- pass 1: gather T into registers, accumulate Y_from_P ----
    float2 t[KNB];
    float ypx = 0.f, ypy = 0.f;
    #pragma unroll
    for (int k = 0; k < KNB; ++k) {
        const int idx  = ks[k];            // wave-uniform load
        const float pk = prow[k];          // wave-uniform load
        t[k] = *(const float2*)&M[(size_t)idx * DIM + d0];
        ypx = fmaf(pk, t[k].x, ypx);
        ypy = fmaf(pk, t[k].y, ypy);
    }

    // xi = lam + rho*(y - yp)
    const float xix = lam.x + RHO * (y.x - ypx);
    const float xiy = lam.y + RHO * (y.y - ypy);

    // ---- scores: s[k] = sum_d T[k][d]*xi[d]  (64-lane butterfly per k) ----
    float s[KNB];
    #pragma unroll
    for (int k = 0; k < KNB; ++k) {
        s[k] = t[k].x * xix + t[k].y * xiy;
    }
    #pragma unroll
    for (int k = 0; k < KNB; ++k) {
        #pragma unroll
        for (int off = 32; off > 0; off >>= 1)
            s[k] += __shfl_xor(s[k], off, 64);
    }
    // now every lane holds all 32 full scores (identical across lanes)

    // ---- softmax(log P - beta*s) == P*exp(-beta*s)/sum, max-subtracted ----
    float smin = s[0];
    #pragma unroll
    for (int k = 1; k < KNB; ++k) smin = fminf(smin, s[k]);

    float esum = 0.f;
    #pragma unroll
    for (int k = 0; k < KNB; ++k) {
        // arg = -beta*(s[k]-smin) <= 0 : no overflow; P>=~3e-5 : no underflow issues
        s[k] = prow[k] * expf(-BETA * (s[k] - smin));
        esum += s[k];
    }
    const float inv = 1.f / esum;

    // ---- pass 2: Y_from_Pnew, outputs ----
    float yp2x = 0.f, yp2y = 0.f;
    #pragma unroll
    for (int k = 0; k < KNB; ++k) {
        const float pn = s[k] * inv;
        yp2x = fmaf(pn, t[k].x, yp2x);
        yp2y = fmaf(pn, t[k].y, yp2y);
    }

    if (lane < KNB)
        Pnew[n * KNB + lane] = s[lane] * inv;

    const float rx = y.x - yp2x;
    const float ry = y.y - yp2y;
    const float lnx = lam.x + RHO * rx;
    const float lny = lam.y + RHO * ry;
    *(float2*)&LamNew[n * DIM + d0] = make_float2(lnx, lny);

    // energy contribution: 0.5*rho*r^2 + lam_new*r  (summed over this lane's 2 dims)
    float c = 0.5f * RHO * (rx * rx + ry * ry) + lnx * rx + lny * ry;
    #pragma unroll
    for (int off = 32; off > 0; off >>= 1)
        c += __shfl_xor(c, off, 64);

    __shared__ float wsum[4];
    if (lane == 0) wsum[wid] = c;
    __syncthreads();
    if (threadIdx.x == 0)
        blockPartials[blockIdx.x] = wsum[0] + wsum[1] + wsum[2] + wsum[3];
}

// Deterministic single-block reduction of the per-block energy partials.
__global__ __launch_bounds__(256) void reduce_energy(
    const float* __restrict__ partials, int nPart, float* __restrict__ out)
{
    __shared__ double sdata[256];
    double acc = 0.0;
    for (int i = threadIdx.x; i < nPart; i += 256)
        acc += (double)partials[i];
    sdata[threadIdx.x] = acc;
    __syncthreads();
    for (int sft = 128; sft > 0; sft >>= 1) {
        if (threadIdx.x < sft) sdata[threadIdx.x] += sdata[threadIdx.x + sft];
        __syncthreads();
    }
    if (threadIdx.x == 0) out[0] = (float)sdata[0];
}

extern "C" void kernel_launch(void* const* d_in, const int* in_sizes, int n_in,
                              void* d_out, int out_size, void* d_ws, size_t ws_size,
                              hipStream_t stream) {
    // inputs in setup_inputs() dict order: M, P, Y, Lam, Kset
    const float* M    = (const float*)d_in[0];
    const float* P    = (const float*)d_in[1];
    const float* Y    = (const float*)d_in[2];
    const float* Lam  = (const float*)d_in[3];
    const int*   Kset = (const int*)d_in[4];

    float* out    = (float*)d_out;
    float* Pnew   = out;                               // N*K floats
    float* LamNew = out + (size_t)N_TOK * KNB;         // N*D floats
    float* energy = out + (size_t)N_TOK * KNB + (size_t)N_TOK * DIM; // 1 float

    float* blockPartials = (float*)d_ws;               // nBlocks floats

    const int rowsPerBlock = 4;
    const int nBlocks = N_TOK / rowsPerBlock;          // 16384

    mirror_main<<<nBlocks, 256, 0, stream>>>(M, P, Y, Lam, Kset,
                                             Pnew, LamNew, blockPartials);
    reduce_energy<<<1, 256, 0, stream>>>(blockPartials, nBlocks, energy);
}

// Round 2
// 210.599 us; speedup vs baseline: 1.1001x; 1.1001x over previous
//
#include <hip/hip_runtime.h>

// Problem constants (from reference setup_inputs)
#define N_TOK 65536
#define KNB 32
#define DIM 128
#define RHO 1.0f
#define BETA 0.5f

// One wave (64 lanes) per row; lane owns dims (2*lane, 2*lane+1).
// Block = 256 threads = 4 rows. launch_bounds(256,3): allow ~170 VGPRs so
// t[32] (64 VGPRs) + score partials stay in registers (measured occupancy
// was only ~3.4 waves/SIMD anyway at VGPR=64, so this costs nothing).
__global__ __launch_bounds__(256, 3) void mirror_main(
    const float* __restrict__ M,
    const float* __restrict__ P,
    const float* __restrict__ Y,
    const float* __restrict__ Lam,
    const int*   __restrict__ Kset,
    float* __restrict__ Pnew,
    float* __restrict__ LamNew,
    float* __restrict__ rowPartials)
{
    const int wid  = threadIdx.x >> 6;     // wave id in block (0..3)
    const int lane = threadIdx.x & 63;
    const int n    = blockIdx.x * 4 + wid; // row index
    const int d0   = lane * 2;

    const float2 y   = *(const float2*)&Y[n * DIM + d0];
    const float2 lam = *(const float2*)&Lam[n * DIM + d0];

    const int*   ks   = &Kset[n * KNB];
    const float* prow = &P[n * KNB];

    // ---- pass 1: gather T into registers, accumulate Y_from_P ----
    float2 t[KNB];
    float ypx = 0.f, ypy = 0.f;
    #pragma unroll
    for (int k = 0; k < KNB; ++k) {
        const int idx  = ks[k];            // wave-uniform (s_load)
        const float pk = prow[k];          // wave-uniform (s_load)
        t[k] = *(const float2*)&M[(size_t)idx * DIM + d0];
        ypx = fmaf(pk, t[k].x, ypx);
        ypy = fmaf(pk, t[k].y, ypy);
    }

    // xi = lam + rho*(y - yp)   (RHO = 1)
    const float xix = lam.x + (y.x - ypx);
    const float xiy = lam.y + (y.y - ypy);

    // ---- per-lane score partials ----
    float v[KNB];
    #pragma unroll
    for (int k = 0; k < KNB; ++k)
        v[k] = t[k].x * xix + t[k].y * xiy;

    // ---- reduce-scatter: 32 shuffles total (vs 192 for 32 butterflies).
    // At level distance d (current value count == d), lanes with (lane&d)
    // keep the upper half of their values; exchange the other half.
    // After all levels lane l holds the FULL score for k = (l>>1).
    #pragma unroll
    for (int d = 32; d >= 2; d >>= 1) {
        const int half = d >> 1;
        const bool upper = (lane & d) != 0;
        #pragma unroll
        for (int j = 0; j < half; ++j) {
            const float send = upper ? v[j] : v[j + half];
            const float keep = upper ? v[j + half] : v[j];
            const float recv = __shfl_xor(send, d, 64);
            v[j] = keep + recv;
        }
    }
    float S = v[0] + __shfl_xor(v[0], 1, 64);
    const int myk = lane >> 1;

    // ---- distributed softmax over k: softmax(log P - beta*S)
    //      == P*exp(-beta*(S - Smin)) / sum.  One expf per lane.
    // k values live in the 32-lane parity group (distances 2..32).
    float m = S;
    #pragma unroll
    for (int d = 2; d <= 32; d <<= 1)
        m = fminf(m, __shfl_xor(m, d, 64));

    const float pk_mine = prow[myk];       // per-lane vector load (coalesced)
    float e = pk_mine * expf(-BETA * (S - m));
    float esum = e;
    #pragma unroll
    for (int d = 2; d <= 32; d <<= 1)
        esum += __shfl_xor(esum, d, 64);

    const float inv = 1.f / esum;
    const float pn_mine = e * inv;
    if ((lane & 1) == 0)
        Pnew[n * KNB + myk] = pn_mine;

    // ---- pass 2: Y_from_Pnew.  Broadcast pn[k] from lane 2k (constant
    // source lane -> v_readlane to SGPR, used as scalar fma operand).
    float yp2x = 0.f, yp2y = 0.f;
    #pragma unroll
    for (int k = 0; k < KNB; ++k) {
        const float pn = __shfl(pn_mine, 2 * k, 64);
        yp2x = fmaf(pn, t[k].x, yp2x);
        yp2y = fmaf(pn, t[k].y, yp2y);
    }

    const float rx = y.x - yp2x;
    const float ry = y.y - yp2y;
    const float lnx = lam.x + rx;          // RHO = 1
    const float lny = lam.y + ry;
    *(float2*)&LamNew[n * DIM + d0] = make_float2(lnx, lny);

    // energy: 0.5*rho*r^2 + lam_new*r summed over this lane's 2 dims
    float c = 0.5f * (rx * rx + ry * ry) + lnx * rx + lny * ry;
    #pragma unroll
    for (int d = 1; d <= 32; d <<= 1)
        c += __shfl_xor(c, d, 64);
    if (lane == 0)
        rowPartials[n] = c;                // one partial per row, no barrier
}

// Deterministic single-block reduction of the per-row energy partials.
__global__ __launch_bounds__(256) void reduce_energy(
    const float* __restrict__ partials, int nPart, float* __restrict__ out)
{
    __shared__ double sdata[256];
    double acc = 0.0;
    for (int i = threadIdx.x; i < nPart; i += 256)
        acc += (double)partials[i];
    sdata[threadIdx.x] = acc;
    __syncthreads();
    for (int sft = 128; sft > 0; sft >>= 1) {
        if (threadIdx.x < sft) sdata[threadIdx.x] += sdata[threadIdx.x + sft];
        __syncthreads();
    }
    if (threadIdx.x == 0) out[0] = (float)sdata[0];
}

extern "C" void kernel_launch(void* const* d_in, const int* in_sizes, int n_in,
                              void* d_out, int out_size, void* d_ws, size_t ws_size,
                              hipStream_t stream) {
    // inputs in setup_inputs() dict order: M, P, Y, Lam, Kset
    const float* M    = (const float*)d_in[0];
    const float* P    = (const float*)d_in[1];
    const float* Y    = (const float*)d_in[2];
    const float* Lam  = (const float*)d_in[3];
    const int*   Kset = (const int*)d_in[4];

    float* out    = (float*)d_out;
    float* Pnew   = out;                               // N*K floats
    float* LamNew = out + (size_t)N_TOK * KNB;         // N*D floats
    float* energy = out + (size_t)N_TOK * KNB + (size_t)N_TOK * DIM; // 1 float

    float* rowPartials = (float*)d_ws;                 // N_TOK floats

    const int rowsPerBlock = 4;
    const int nBlocks = N_TOK / rowsPerBlock;          // 16384

    mirror_main<<<nBlocks, 256, 0, stream>>>(M, P, Y, Lam, Kset,
                                             Pnew, LamNew, rowPartials);
    reduce_energy<<<1, 256, 0, stream>>>(rowPartials, N_TOK, energy);
}

// Round 3
// 152.357 us; speedup vs baseline: 1.5207x; 1.3823x over previous
//
#include <hip/hip_runtime.h>

// Problem constants (from reference setup_inputs)
#define N_TOK 65536
#define KNB 32
#define DIM 128
#define BETA 0.5f
// RHO == 1.0f folded into the arithmetic.

// One wave (64 lanes) per row; lane owns dims (2*lane, 2*lane+1).
// Block = 256 threads = 4 rows. launch_bounds(256,3): VGPR cap ~170 so the
// 64-VGPR t[] tile plus score partials fit without spilling.
__global__ __launch_bounds__(256, 3) void mirror_main(
    const float* __restrict__ M,
    const float* __restrict__ P,
    const float* __restrict__ Y,
    const float* __restrict__ Lam,
    const int*   __restrict__ Kset,
    float* __restrict__ Pnew,
    float* __restrict__ LamNew,
    float* __restrict__ blockPartials)
{
    const int wid  = threadIdx.x >> 6;     // wave id in block (0..3)
    const int lane = threadIdx.x & 63;
    const int n    = blockIdx.x * 4 + wid; // row index
    const int d0   = lane * 2;

    const float2 y   = *(const float2*)&Y[n * DIM + d0];
    const float2 lam = *(const float2*)&Lam[n * DIM + d0];

    const int*   ks   = &Kset[n * KNB];
    const float* prow = &P[n * KNB];

    // ---- single gather: T into registers, accumulate Y_from_P ----
    float2 t[KNB];
    float ypx = 0.f, ypy = 0.f;
    #pragma unroll
    for (int k = 0; k < KNB; ++k) {
        const int idx  = ks[k];            // wave-uniform (s_load)
        t[k] = *(const float2*)&M[(size_t)idx * DIM + d0];
        // Launder through opaque asm: compiler may NOT rematerialize these
        // from M later (round-1 codegen re-gathered 3x, VGPR_Count=60).
        asm("" : "+v"(t[k].x), "+v"(t[k].y));
        const float pk = prow[k];          // wave-uniform (s_load)
        ypx = fmaf(pk, t[k].x, ypx);
        ypy = fmaf(pk, t[k].y, ypy);
    }

    // xi = lam + rho*(y - yp)   (RHO = 1)
    const float xix = lam.x + (y.x - ypx);
    const float xiy = lam.y + (y.y - ypy);

    // ---- per-lane score partials ----
    float v[KNB];
    #pragma unroll
    for (int k = 0; k < KNB; ++k)
        v[k] = t[k].x * xix + t[k].y * xiy;

    // ---- reduce-scatter: 32 shuffles total. After all levels lane l holds
    // the FULL score for k = (l>>1).
    #pragma unroll
    for (int d = 32; d >= 2; d >>= 1) {
        const int half = d >> 1;
        const bool upper = (lane & d) != 0;
        #pragma unroll
        for (int j = 0; j < half; ++j) {
            const float send = upper ? v[j] : v[j + half];
            const float keep = upper ? v[j + half] : v[j];
            const float recv = __shfl_xor(send, d, 64);
            v[j] = keep + recv;
        }
    }
    float S = v[0] + __shfl_xor(v[0], 1, 64);
    const int myk = lane >> 1;

    // ---- distributed softmax: softmax(log P - beta*S) ----
    float m = S;
    #pragma unroll
    for (int d = 2; d <= 32; d <<= 1)
        m = fminf(m, __shfl_xor(m, d, 64));

    const float pk_mine = prow[myk];
    float e = pk_mine * expf(-BETA * (S - m));
    float esum = e;
    #pragma unroll
    for (int d = 2; d <= 32; d <<= 1)
        esum += __shfl_xor(esum, d, 64);

    const float inv = 1.f / esum;
    const float pn_mine = e * inv;
    if ((lane & 1) == 0)
        Pnew[n * KNB + myk] = pn_mine;

    // ---- pass 2: Y_from_Pnew. readlane -> SGPR broadcast (no DS ops). ----
    float yp2x = 0.f, yp2y = 0.f;
    #pragma unroll
    for (int k = 0; k < KNB; ++k) {
        const float pn = __uint_as_float(
            __builtin_amdgcn_readlane(__float_as_uint(pn_mine), 2 * k));
        yp2x = fmaf(pn, t[k].x, yp2x);
        yp2y = fmaf(pn, t[k].y, yp2y);
    }

    const float rx = y.x - yp2x;
    const float ry = y.y - yp2y;
    const float lnx = lam.x + rx;          // RHO = 1
    const float lny = lam.y + ry;
    *(float2*)&LamNew[n * DIM + d0] = make_float2(lnx, lny);

    // energy: 0.5*rho*r^2 + lam_new*r summed over this lane's 2 dims
    float c = 0.5f * (rx * rx + ry * ry) + lnx * rx + lny * ry;
    #pragma unroll
    for (int d = 1; d <= 32; d <<= 1)
        c += __shfl_xor(c, d, 64);

    __shared__ float wsum[4];
    if (lane == 0) wsum[wid] = c;
    __syncthreads();
    if (threadIdx.x == 0)
        blockPartials[blockIdx.x] = wsum[0] + wsum[1] + wsum[2] + wsum[3];
}

// Stage 1: 64 blocks x 256 threads; block b sums blockPartials[b*256..+255].
__global__ __launch_bounds__(256) void reduce_stage1(
    const float* __restrict__ in, float* __restrict__ out)
{
    __shared__ float s[256];
    s[threadIdx.x] = in[blockIdx.x * 256 + threadIdx.x];
    __syncthreads();
    for (int sft = 128; sft > 0; sft >>= 1) {
        if (threadIdx.x < sft) s[threadIdx.x] += s[threadIdx.x + sft];
        __syncthreads();
    }
    if (threadIdx.x == 0) out[blockIdx.x] = s[0];
}

// Stage 2: one wave sums the 64 stage-1 partials.
__global__ __launch_bounds__(64) void reduce_stage2(
    const float* __restrict__ in, float* __restrict__ out)
{
    float v = in[threadIdx.x];
    #pragma unroll
    for (int d = 1; d <= 32; d <<= 1)
        v += __shfl_xor(v, d, 64);
    if (threadIdx.x == 0) out[0] = v;
}

extern "C" void kernel_launch(void* const* d_in, const int* in_sizes, int n_in,
                              void* d_out, int out_size, void* d_ws, size_t ws_size,
                              hipStream_t stream) {
    // inputs in setup_inputs() dict order: M, P, Y, Lam, Kset
    const float* M    = (const float*)d_in[0];
    const float* P    = (const float*)d_in[1];
    const float* Y    = (const float*)d_in[2];
    const float* Lam  = (const float*)d_in[3];
    const int*   Kset = (const int*)d_in[4];

    float* out    = (float*)d_out;
    float* Pnew   = out;                               // N*K floats
    float* LamNew = out + (size_t)N_TOK * KNB;         // N*D floats
    float* energy = out + (size_t)N_TOK * KNB + (size_t)N_TOK * DIM; // 1 float

    const int nBlocks = N_TOK / 4;                     // 16384
    float* blockPartials = (float*)d_ws;               // 16384 floats
    float* part2         = blockPartials + nBlocks;    // 64 floats (ws total ~66KB)

    mirror_main<<<nBlocks, 256, 0, stream>>>(M, P, Y, Lam, Kset,
                                             Pnew, LamNew, blockPartials);
    reduce_stage1<<<64, 256, 0, stream>>>(blockPartials, part2);
    reduce_stage2<<<1, 64, 0, stream>>>(part2, energy);
}